// Round 1
// baseline (166.400 us; speedup 1.0000x reference)
//
#include <hip/hip_runtime.h>
#include <cstddef>

// ---------------------------------------------------------------------------
// MHA block: y = attn(x@Wqkv+b) @ Wo + bo   (B=16,T=512,C=1024,H=16,hd=64)
// bf16 MFMA pipeline. Shapes fixed.
// ---------------------------------------------------------------------------

#define B_  16
#define T_  512
#define C_  1024
#define H_  16
#define HD_ 64

typedef __bf16 bf16x8 __attribute__((ext_vector_type(8)));
typedef float  f32x4  __attribute__((ext_vector_type(4)));

__device__ __forceinline__ void gload16(const void* g, void* lds) {
  __builtin_amdgcn_global_load_lds(
      (const __attribute__((address_space(1))) unsigned int*)g,
      (__attribute__((address_space(3))) unsigned int*)lds, 16, 0, 0);
}

// ------------------------- convert x: fp32 -> bf16 --------------------------
__global__ void cvt_kernel(const float* __restrict__ in, __bf16* __restrict__ out, int n) {
  int i = (blockIdx.x * 256 + threadIdx.x) * 8;
  if (i >= n) return;
  float4 f0 = *(const float4*)&in[i];
  float4 f1 = *(const float4*)&in[i + 4];
  bf16x8 o;
  o[0] = (__bf16)f0.x; o[1] = (__bf16)f0.y; o[2] = (__bf16)f0.z; o[3] = (__bf16)f0.w;
  o[4] = (__bf16)f1.x; o[5] = (__bf16)f1.y; o[6] = (__bf16)f1.z; o[7] = (__bf16)f1.w;
  *(bf16x8*)&out[i] = o;
}

// -------------- transpose+convert: w[K][N] fp32 -> wt[N][K] bf16 ------------
__global__ void tconv_kernel(const float* __restrict__ w, __bf16* __restrict__ wt,
                             int K, int N) {
  __shared__ float tile[32][33];
  int tx = threadIdx.x, ty = threadIdx.y;          // block (32,8)
  int n0 = blockIdx.x * 32, k0 = blockIdx.y * 32;
  #pragma unroll
  for (int i = 0; i < 4; ++i) {
    int r = ty + i * 8;
    tile[r][tx] = w[(size_t)(k0 + r) * N + n0 + tx];
  }
  __syncthreads();
  #pragma unroll
  for (int i = 0; i < 4; ++i) {
    int r = ty + i * 8;
    wt[(size_t)(n0 + r) * K + k0 + tx] = (__bf16)tile[tx][r];
  }
}

// ---------------------------------------------------------------------------
// GEMM: C[M][N] = A[M][K] @ BT[N][K]^T + bias[N]
// 128x128 tile, BK=64, 4 waves (2x2), each wave 64x64 via 4x4 16x16x32 MFMA.
// Double-buffered LDS, global_load_lds width-16 staging, prefetch-then-compute.
// EPI=0: split into q/k/v bf16 buffers laid out [B,H,T,HD].
// EPI=1: fp32 output at [M][N].
// ---------------------------------------------------------------------------
template<int EPI>
__global__ __launch_bounds__(256, 2) void gemm_kernel(
    const __bf16* __restrict__ A, const __bf16* __restrict__ BT,
    const float* __restrict__ bias, int M, int N, int K,
    __bf16* __restrict__ oq, __bf16* __restrict__ okk, __bf16* __restrict__ ov,
    float* __restrict__ out32)
{
  __shared__ __bf16 As[2][128 * 64];
  __shared__ __bf16 Bs[2][128 * 64];
  const int tid  = threadIdx.x;
  const int lane = tid & 63;
  const int wid  = tid >> 6;
  const int wr = wid >> 1, wc = wid & 1;
  const int m0 = blockIdx.x * 128, n0 = blockIdx.y * 128;
  const int lr = lane & 15, lg = lane >> 4;

  f32x4 acc[4][4] = {};
  const int nk = K >> 6;

  auto stage = [&](int b, int kt) {
    const __bf16* ga = A  + (size_t)m0 * K + kt * 64;
    const __bf16* gb = BT + (size_t)n0 * K + kt * 64;
    #pragma unroll
    for (int p = 0; p < 4; ++p) {
      int row = p * 32 + wid * 8 + (lane >> 3);
      int ce  = (lane & 7) * 8;
      gload16(ga + (size_t)row * K + ce, &As[b][(p * 32 + wid * 8) * 64]);
      gload16(gb + (size_t)row * K + ce, &Bs[b][(p * 32 + wid * 8) * 64]);
    }
  };

  stage(0, 0);
  __syncthreads();
  for (int kt = 0; kt < nk; ++kt) {
    int cur = kt & 1;
    if (kt + 1 < nk) stage(cur ^ 1, kt + 1);     // prefetch overlaps compute
    const __bf16* as = As[cur];
    const __bf16* bs = Bs[cur];
    #pragma unroll
    for (int s = 0; s < 2; ++s) {
      bf16x8 a[4], b[4];
      #pragma unroll
      for (int i = 0; i < 4; ++i) {
        a[i] = *(const bf16x8*)&as[(wr * 64 + i * 16 + lr) * 64 + s * 32 + lg * 8];
        b[i] = *(const bf16x8*)&bs[(wc * 64 + i * 16 + lr) * 64 + s * 32 + lg * 8];
      }
      #pragma unroll
      for (int mi = 0; mi < 4; ++mi)
        #pragma unroll
        for (int ni = 0; ni < 4; ++ni)
          acc[mi][ni] = __builtin_amdgcn_mfma_f32_16x16x32_bf16(
              a[mi], b[ni], acc[mi][ni], 0, 0, 0);
    }
    __syncthreads();                              // drain prefetch + LDS reuse
  }

  // epilogue: D row = (lg*4+j), col = lr within each 16x16 frag
  #pragma unroll
  for (int ni = 0; ni < 4; ++ni) {
    int n = n0 + wc * 64 + ni * 16 + lr;
    float bv = bias[n];
    if (EPI == 0) {
      int which = n >> 10;
      __bf16* dst = (which == 0) ? oq : (which == 1) ? okk : ov;
      int h = (n >> 6) & 15, d = n & 63;
      #pragma unroll
      for (int mi = 0; mi < 4; ++mi)
        #pragma unroll
        for (int j = 0; j < 4; ++j) {
          int m = m0 + wr * 64 + mi * 16 + lg * 4 + j;
          int bb = m >> 9, t = m & 511;
          dst[(size_t)((bb * H_ + h) * T_ + t) * HD_ + d] =
              (__bf16)(acc[mi][ni][j] + bv);
        }
    } else {
      #pragma unroll
      for (int mi = 0; mi < 4; ++mi)
        #pragma unroll
        for (int j = 0; j < 4; ++j) {
          int m = m0 + wr * 64 + mi * 16 + lg * 4 + j;
          out32[(size_t)m * N + n] = acc[mi][ni][j] + bv;
        }
    }
  }
}

// ---------------------------------------------------------------------------
// Flash attention (causal). Grid (B*H, T/64). 4 waves, each wave 16 q-rows.
// K chunk [64][72] row-major (padded), V chunk transposed [64][72].
// S = mfma(Q, K): D rows = q (lg*4+j), cols = kv (lr). Online softmax with
// 16-lane shfl_xor reduce. P restaged through per-wave LDS to A-layout.
// ---------------------------------------------------------------------------
__global__ __launch_bounds__(256, 2) void attn_kernel(
    const __bf16* __restrict__ qb, const __bf16* __restrict__ kb,
    const __bf16* __restrict__ vb, __bf16* __restrict__ y)
{
  __shared__ __attribute__((aligned(16))) __bf16 Ks[64][72];
  __shared__ __attribute__((aligned(16))) __bf16 Vt[64][72];
  __shared__ __attribute__((aligned(16))) __bf16 Ps[4][16][72];

  const int tid = threadIdx.x, lane = tid & 63, w = tid >> 6;
  const int lr = lane & 15, lg = lane >> 4;
  const int bh = blockIdx.x, qt = blockIdx.y;
  const size_t base = (size_t)bh * T_ * HD_;
  const int q0 = qt * 64 + w * 16;
  const float SCALE = 0.03125f;                   // 1/sqrt(1024)
  const float L2E = 1.44269504088896f;

  bf16x8 qf[2];
  #pragma unroll
  for (int s = 0; s < 2; ++s)
    qf[s] = *(const bf16x8*)&qb[base + (size_t)(q0 + lr) * HD_ + s * 32 + lg * 8];

  f32x4 acc[4] = {};
  float mrun[4] = { -__builtin_inff(), -__builtin_inff(),
                    -__builtin_inff(), -__builtin_inff() };
  float lrun[4] = { 0.f, 0.f, 0.f, 0.f };

  for (int c = 0; c <= qt; ++c) {
    // ---- stage K (row-major, padded) and V (transposed) ----
    #pragma unroll
    for (int p = 0; p < 2; ++p) {
      int t8 = p * 256 + tid;
      int r = t8 >> 3, col = (t8 & 7) * 8;
      bf16x8 kk = *(const bf16x8*)&kb[base + c * 4096 + t8 * 8];
      *(bf16x8*)&Ks[r][col] = kk;
      bf16x8 vv = *(const bf16x8*)&vb[base + c * 4096 + t8 * 8];
      #pragma unroll
      for (int i = 0; i < 8; ++i) Vt[col + i][r] = vv[i];
    }
    __syncthreads();

    // ---- S = Q K^T (16 q x 64 kv) ----
    f32x4 sc[4] = {};
    #pragma unroll
    for (int s = 0; s < 2; ++s) {
      #pragma unroll
      for (int cc = 0; cc < 4; ++cc) {
        bf16x8 kf = *(const bf16x8*)&Ks[cc * 16 + lr][s * 32 + lg * 8];
        sc[cc] = __builtin_amdgcn_mfma_f32_16x16x32_bf16(qf[s], kf, sc[cc], 0, 0, 0);
      }
    }

    // ---- scale + causal mask ----
    #pragma unroll
    for (int cc = 0; cc < 4; ++cc)
      #pragma unroll
      for (int j = 0; j < 4; ++j) {
        float v = sc[cc][j] * SCALE;
        if (c == qt) {
          int kv = c * 64 + cc * 16 + lr;
          int qr = q0 + lg * 4 + j;
          if (kv > qr) v = -__builtin_inff();
        }
        sc[cc][j] = v;
      }

    // ---- online softmax ----
    float mx[4];
    #pragma unroll
    for (int j = 0; j < 4; ++j)
      mx[j] = fmaxf(fmaxf(sc[0][j], sc[1][j]), fmaxf(sc[2][j], sc[3][j]));
    #pragma unroll
    for (int msk = 1; msk <= 8; msk <<= 1)
      #pragma unroll
      for (int j = 0; j < 4; ++j)
        mx[j] = fmaxf(mx[j], __shfl_xor(mx[j], msk, 64));
    float corr[4];
    #pragma unroll
    for (int j = 0; j < 4; ++j) {
      float nm = fmaxf(mrun[j], mx[j]);
      corr[j] = exp2f((mrun[j] - nm) * L2E);
      mrun[j] = nm;
    }
    #pragma unroll
    for (int cc = 0; cc < 4; ++cc)
      #pragma unroll
      for (int j = 0; j < 4; ++j)
        sc[cc][j] = exp2f((sc[cc][j] - mrun[j]) * L2E);
    float rs[4];
    #pragma unroll
    for (int j = 0; j < 4; ++j)
      rs[j] = sc[0][j] + sc[1][j] + sc[2][j] + sc[3][j];
    #pragma unroll
    for (int msk = 1; msk <= 8; msk <<= 1)
      #pragma unroll
      for (int j = 0; j < 4; ++j)
        rs[j] += __shfl_xor(rs[j], msk, 64);
    #pragma unroll
    for (int j = 0; j < 4; ++j)
      lrun[j] = lrun[j] * corr[j] + rs[j];
    #pragma unroll
    for (int dd = 0; dd < 4; ++dd)
      #pragma unroll
      for (int j = 0; j < 4; ++j)
        acc[dd][j] *= corr[j];

    // ---- P: C-layout -> A-layout via per-wave LDS ----
    #pragma unroll
    for (int cc = 0; cc < 4; ++cc)
      #pragma unroll
      for (int j = 0; j < 4; ++j)
        Ps[w][lg * 4 + j][cc * 16 + lr] = (__bf16)sc[cc][j];

    // ---- O += P V ----
    #pragma unroll
    for (int s = 0; s < 2; ++s) {
      bf16x8 pa = *(const bf16x8*)&Ps[w][lr][s * 32 + lg * 8];
      #pragma unroll
      for (int dd = 0; dd < 4; ++dd) {
        bf16x8 vf = *(const bf16x8*)&Vt[dd * 16 + lr][s * 32 + lg * 8];
        acc[dd] = __builtin_amdgcn_mfma_f32_16x16x32_bf16(pa, vf, acc[dd], 0, 0, 0);
      }
    }
    __syncthreads();   // before next chunk overwrites Ks/Vt
  }

  // ---- normalize + write y[B,T,C] bf16 ----
  const int b = bh >> 4, h = bh & 15;
  #pragma unroll
  for (int dd = 0; dd < 4; ++dd)
    #pragma unroll
    for (int j = 0; j < 4; ++j) {
      int t = q0 + lg * 4 + j;
      int d = dd * 16 + lr;
      y[((size_t)(b * T_ + t)) * C_ + h * HD_ + d] = (__bf16)(acc[dd][j] / lrun[j]);
    }
}

// ---------------------------------------------------------------------------
extern "C" void kernel_launch(void* const* d_in, const int* in_sizes, int n_in,
                              void* d_out, int out_size, void* d_ws, size_t ws_size,
                              hipStream_t stream) {
  const float* x    = (const float*)d_in[0];
  const float* wqkv = (const float*)d_in[1];
  const float* bqkv = (const float*)d_in[2];
  const float* wo   = (const float*)d_in[3];
  const float* bo   = (const float*)d_in[4];
  float* out = (float*)d_out;

  char* ws = (char*)d_ws;
  const size_t MB = 1u << 20;
  __bf16* xb   = (__bf16*)(ws);              // 16 MB  x bf16 [8192][1024]
  __bf16* wqt  = (__bf16*)(ws + 16 * MB);    //  6 MB  w_qkv^T bf16 [3072][1024]
  __bf16* wot  = (__bf16*)(ws + 22 * MB);    //  2 MB  w_o^T bf16 [1024][1024]
  __bf16* qbuf = (__bf16*)(ws + 24 * MB);    // 16 MB  Q [B,H,T,HD]
  __bf16* kbuf = (__bf16*)(ws + 40 * MB);    // 16 MB  K
  __bf16* vbuf = (__bf16*)(ws + 56 * MB);    // 16 MB  V
  __bf16* ybuf = (__bf16*)(ws + 72 * MB);    // 16 MB  attn out [B,T,C]

  const int NX = B_ * T_ * C_;               // 8388608
  cvt_kernel<<<NX / (256 * 8), 256, 0, stream>>>(x, xb, NX);
  tconv_kernel<<<dim3(3 * C_ / 32, C_ / 32), dim3(32, 8), 0, stream>>>(wqkv, wqt, C_, 3 * C_);
  tconv_kernel<<<dim3(C_ / 32, C_ / 32), dim3(32, 8), 0, stream>>>(wo, wot, C_, C_);

  gemm_kernel<0><<<dim3(64, 24), 256, 0, stream>>>(
      xb, wqt, bqkv, B_ * T_, 3 * C_, C_, qbuf, kbuf, vbuf, nullptr);

  attn_kernel<<<dim3(B_ * H_, T_ / 64), 256, 0, stream>>>(qbuf, kbuf, vbuf, ybuf);

  gemm_kernel<1><<<dim3(64, 8), 256, 0, stream>>>(
      ybuf, wot, bo, B_ * T_, C_, C_, nullptr, nullptr, nullptr, out);
}

// Round 2
// 162.472 us; speedup vs baseline: 1.0242x; 1.0242x over previous
//
#include <hip/hip_runtime.h>
#include <cstddef>

// ---------------------------------------------------------------------------
// MHA block: y = attn(x@Wqkv+b) @ Wo + bo   (B=16,T=512,C=1024,H=16,hd=64)
// bf16 MFMA pipeline. R2: 8-phase counted-vmcnt 256x128 GEMM (T2+T3+T4+T5).
// ---------------------------------------------------------------------------

#define B_  16
#define T_  512
#define C_  1024
#define H_  16
#define HD_ 64

typedef __bf16 bf16x8 __attribute__((ext_vector_type(8)));
typedef float  f32x4  __attribute__((ext_vector_type(4)));

__device__ __forceinline__ void gload16(const void* g, void* lds) {
  __builtin_amdgcn_global_load_lds(
      (const __attribute__((address_space(1))) unsigned int*)g,
      (__attribute__((address_space(3))) unsigned int*)lds, 16, 0, 0);
}

// ------------------------- convert x: fp32 -> bf16 --------------------------
__global__ void cvt_kernel(const float* __restrict__ in, __bf16* __restrict__ out, int n) {
  int i = (blockIdx.x * 256 + threadIdx.x) * 8;
  if (i >= n) return;
  float4 f0 = *(const float4*)&in[i];
  float4 f1 = *(const float4*)&in[i + 4];
  bf16x8 o;
  o[0] = (__bf16)f0.x; o[1] = (__bf16)f0.y; o[2] = (__bf16)f0.z; o[3] = (__bf16)f0.w;
  o[4] = (__bf16)f1.x; o[5] = (__bf16)f1.y; o[6] = (__bf16)f1.z; o[7] = (__bf16)f1.w;
  *(bf16x8*)&out[i] = o;
}

// -------------- transpose+convert: w[K][N] fp32 -> wt[N][K] bf16 ------------
__global__ void tconv_kernel(const float* __restrict__ w, __bf16* __restrict__ wt,
                             int K, int N) {
  __shared__ float tile[32][33];
  int tx = threadIdx.x, ty = threadIdx.y;          // block (32,8)
  int n0 = blockIdx.x * 32, k0 = blockIdx.y * 32;
  #pragma unroll
  for (int i = 0; i < 4; ++i) {
    int r = ty + i * 8;
    tile[r][tx] = w[(size_t)(k0 + r) * N + n0 + tx];
  }
  __syncthreads();
  #pragma unroll
  for (int i = 0; i < 4; ++i) {
    int r = ty + i * 8;
    wt[(size_t)(n0 + r) * K + k0 + tx] = (__bf16)tile[tx][r];
  }
}

// ---------------------------------------------------------------------------
// 8-phase GEMM: C[M][N] = A[M][K] @ BT[N][K]^T + bias[N]
// Tile 256x128, BK=64, 8 waves (4M x 2N), 512 threads, 96 KiB dynamic LDS.
// LDS: A dbuf 2x32KB @0, B dbuf 2x16KB @64KB. Rows are 128B; fragment reads
// use XOR swizzle byte^=((row&7)<<4); staging pre-swizzles the GLOBAL source
// so global_load_lds dest stays linear (rule 21).
// Schedule per K-tile t (buf cur=t&1):
//   ph0: ds_read all A frags + B frags 0-1 ; 8 MFMA q(0,0) ; barrier
//   ph1: ds_read B frags 2-3 ; 8 MFMA q(0,1) ; lgkmcnt(0) ; barrier
//   ph2: issue 3 global_load_lds (tile t+2 -> buf cur) ; 8 MFMA q(1,0) ; barrier
//   ph3: issue 3 more ; 8 MFMA q(1,1) ; vmcnt(6) ; barrier   (counted, never 0)
// ---------------------------------------------------------------------------
#define PHASE_MFMA(mh, nh)                                                     \
  __builtin_amdgcn_s_setprio(1);                                               \
  _Pragma("unroll")                                                            \
  for (int mi = 0; mi < 2; ++mi)                                               \
    _Pragma("unroll")                                                          \
    for (int ni = 0; ni < 2; ++ni)                                             \
      _Pragma("unroll")                                                        \
      for (int ks = 0; ks < 2; ++ks)                                           \
        acc[(mh)*2+mi][(nh)*2+ni] = __builtin_amdgcn_mfma_f32_16x16x32_bf16(   \
            a[(mh)*2+mi][ks], b[(nh)*2+ni][ks], acc[(mh)*2+mi][(nh)*2+ni],     \
            0, 0, 0);                                                          \
  __builtin_amdgcn_s_setprio(0);

template<int EPI>
__global__ __launch_bounds__(512, 2) void gemm8_kernel(
    const __bf16* __restrict__ A, const __bf16* __restrict__ BT,
    const float* __restrict__ bias, int M, int N, int K, int NBn,
    __bf16* __restrict__ oq, __bf16* __restrict__ okk, __bf16* __restrict__ ov,
    float* __restrict__ out32)
{
  extern __shared__ __align__(16) char lds[];
  const int tid = threadIdx.x, lane = tid & 63, wid = tid >> 6;
  const int wm = wid >> 1, wn = wid & 1;          // wave grid 4M x 2N
  const int lr = lane & 15, lg = lane >> 4;

  const int id = blockIdx.x;
  const int bx = id / NBn, by = id % NBn;
  const int m0 = bx * 256, n0 = by * 128;

  // staging lane constants: each issue = 512 lanes x 16B = 8KB = 64 rows
  const int r8  = wid * 8 + (lane >> 3);                 // row within 64-row chunk
  const int csw = ((lane & 7) ^ ((lane >> 3) & 7)) * 8;  // pre-swizzled col (elems)

  auto stage_lo = [&](int sb, int kt) {                  // A issues 0..2
    const __bf16* ga = A + (size_t)m0 * K + (size_t)kt * 64;
    char* la = lds + sb * 32768;
    #pragma unroll
    for (int i = 0; i < 3; ++i)
      gload16(ga + (size_t)(i * 64 + r8) * K + csw, la + i * 8192 + wid * 1024);
  };
  auto stage_hi = [&](int sb, int kt) {                  // A issue 3 + B issues 0..1
    const __bf16* ga = A  + (size_t)m0 * K + (size_t)kt * 64;
    const __bf16* gb = BT + (size_t)n0 * K + (size_t)kt * 64;
    char* la = lds + sb * 32768;
    char* lb = lds + 65536 + sb * 16384;
    gload16(ga + (size_t)(192 + r8) * K + csw, la + 3 * 8192 + wid * 1024);
    #pragma unroll
    for (int i = 0; i < 2; ++i)
      gload16(gb + (size_t)(i * 64 + r8) * K + csw, lb + i * 8192 + wid * 1024);
  };

  f32x4 acc[4][4] = {};
  const int nt = K >> 6;

  stage_lo(0, 0); stage_hi(0, 0);
  stage_lo(1, 1); stage_hi(1, 1);
  asm volatile("s_waitcnt vmcnt(6)" ::: "memory");   // tile 0 landed, tile 1 in flight
  __builtin_amdgcn_s_barrier();

  for (int t = 0; t < nt; ++t) {
    const int cur = t & 1;
    const char* la = lds + cur * 32768;
    const char* lb = lds + 65536 + cur * 16384;
    bf16x8 a[4][2], b[4][2];

    // ---- phase 0: all A frags + B frags 0-1; MFMA quadrant (0,0) ----
    #pragma unroll
    for (int mf = 0; mf < 4; ++mf)
      #pragma unroll
      for (int ks = 0; ks < 2; ++ks) {
        int row = wm * 64 + mf * 16 + lr;
        a[mf][ks] = *(const bf16x8*)(la + row * 128 + (((ks << 2) + lg) ^ (lr & 7)) * 16);
      }
    #pragma unroll
    for (int nf = 0; nf < 2; ++nf)
      #pragma unroll
      for (int ks = 0; ks < 2; ++ks) {
        int row = wn * 64 + nf * 16 + lr;
        b[nf][ks] = *(const bf16x8*)(lb + row * 128 + (((ks << 2) + lg) ^ (lr & 7)) * 16);
      }
    PHASE_MFMA(0, 0);
    __builtin_amdgcn_s_barrier();

    // ---- phase 1: B frags 2-3; MFMA quadrant (0,1) ----
    #pragma unroll
    for (int nf = 2; nf < 4; ++nf)
      #pragma unroll
      for (int ks = 0; ks < 2; ++ks) {
        int row = wn * 64 + nf * 16 + lr;
        b[nf][ks] = *(const bf16x8*)(lb + row * 128 + (((ks << 2) + lg) ^ (lr & 7)) * 16);
      }
    PHASE_MFMA(0, 1);
    asm volatile("s_waitcnt lgkmcnt(0)" ::: "memory");  // all LDS reads retired
    __builtin_amdgcn_s_barrier();                       // -> safe to overwrite buf

    // ---- phase 2: prefetch t+2 (first half) ; MFMA quadrant (1,0) ----
    if (t + 2 < nt) stage_lo(cur, t + 2);
    PHASE_MFMA(1, 0);
    __builtin_amdgcn_s_barrier();

    // ---- phase 3: prefetch t+2 (second half) ; MFMA quadrant (1,1) ----
    if (t + 2 < nt) stage_hi(cur, t + 2);
    PHASE_MFMA(1, 1);
    if (t + 2 < nt) { asm volatile("s_waitcnt vmcnt(6)" ::: "memory"); }
    else            { asm volatile("s_waitcnt vmcnt(0)" ::: "memory"); }
    __builtin_amdgcn_s_barrier();
  }

  // ---- epilogue ----
  #pragma unroll
  for (int nf = 0; nf < 4; ++nf) {
    int n = n0 + wn * 64 + nf * 16 + lr;
    float bv = bias[n];
    if (EPI == 0) {
      int which = n >> 10;
      __bf16* dst = (which == 0) ? oq : (which == 1) ? okk : ov;
      int h = (n >> 6) & 15, d = n & 63;
      #pragma unroll
      for (int mf = 0; mf < 4; ++mf)
        #pragma unroll
        for (int j = 0; j < 4; ++j) {
          int m = m0 + wm * 64 + mf * 16 + lg * 4 + j;
          int bb = m >> 9, tt = m & 511;
          dst[(size_t)((bb * H_ + h) * T_ + tt) * HD_ + d] =
              (__bf16)(acc[mf][nf][j] + bv);
        }
    } else {
      #pragma unroll
      for (int mf = 0; mf < 4; ++mf)
        #pragma unroll
        for (int j = 0; j < 4; ++j) {
          int m = m0 + wm * 64 + mf * 16 + lg * 4 + j;
          out32[(size_t)m * N + n] = acc[mf][nf][j] + bv;
        }
    }
  }
}

// ---------------------------------------------------------------------------
// Flash attention (causal). Grid (B*H, T/64). 4 waves, each wave 16 q-rows.
// ---------------------------------------------------------------------------
__global__ __launch_bounds__(256, 2) void attn_kernel(
    const __bf16* __restrict__ qb, const __bf16* __restrict__ kb,
    const __bf16* __restrict__ vb, __bf16* __restrict__ y)
{
  __shared__ __attribute__((aligned(16))) __bf16 Ks[64][72];
  __shared__ __attribute__((aligned(16))) __bf16 Vt[64][72];
  __shared__ __attribute__((aligned(16))) __bf16 Ps[4][16][72];

  const int tid = threadIdx.x, lane = tid & 63, w = tid >> 6;
  const int lr = lane & 15, lg = lane >> 4;
  const int bh = blockIdx.x, qt = blockIdx.y;
  const size_t base = (size_t)bh * T_ * HD_;
  const int q0 = qt * 64 + w * 16;
  const float SCALE = 0.03125f;                   // 1/sqrt(1024)
  const float L2E = 1.44269504088896f;

  bf16x8 qf[2];
  #pragma unroll
  for (int s = 0; s < 2; ++s)
    qf[s] = *(const bf16x8*)&qb[base + (size_t)(q0 + lr) * HD_ + s * 32 + lg * 8];

  f32x4 acc[4] = {};
  float mrun[4] = { -__builtin_inff(), -__builtin_inff(),
                    -__builtin_inff(), -__builtin_inff() };
  float lrun[4] = { 0.f, 0.f, 0.f, 0.f };

  for (int c = 0; c <= qt; ++c) {
    #pragma unroll
    for (int p = 0; p < 2; ++p) {
      int t8 = p * 256 + tid;
      int r = t8 >> 3, col = (t8 & 7) * 8;
      bf16x8 kk = *(const bf16x8*)&kb[base + c * 4096 + t8 * 8];
      *(bf16x8*)&Ks[r][col] = kk;
      bf16x8 vv = *(const bf16x8*)&vb[base + c * 4096 + t8 * 8];
      #pragma unroll
      for (int i = 0; i < 8; ++i) Vt[col + i][r] = vv[i];
    }
    __syncthreads();

    f32x4 sc[4] = {};
    #pragma unroll
    for (int s = 0; s < 2; ++s) {
      #pragma unroll
      for (int cc = 0; cc < 4; ++cc) {
        bf16x8 kf = *(const bf16x8*)&Ks[cc * 16 + lr][s * 32 + lg * 8];
        sc[cc] = __builtin_amdgcn_mfma_f32_16x16x32_bf16(qf[s], kf, sc[cc], 0, 0, 0);
      }
    }

    #pragma unroll
    for (int cc = 0; cc < 4; ++cc)
      #pragma unroll
      for (int j = 0; j < 4; ++j) {
        float v = sc[cc][j] * SCALE;
        if (c == qt) {
          int kv = c * 64 + cc * 16 + lr;
          int qr = q0 + lg * 4 + j;
          if (kv > qr) v = -__builtin_inff();
        }
        sc[cc][j] = v;
      }

    float mx[4];
    #pragma unroll
    for (int j = 0; j < 4; ++j)
      mx[j] = fmaxf(fmaxf(sc[0][j], sc[1][j]), fmaxf(sc[2][j], sc[3][j]));
    #pragma unroll
    for (int msk = 1; msk <= 8; msk <<= 1)
      #pragma unroll
      for (int j = 0; j < 4; ++j)
        mx[j] = fmaxf(mx[j], __shfl_xor(mx[j], msk, 64));
    float corr[4];
    #pragma unroll
    for (int j = 0; j < 4; ++j) {
      float nm = fmaxf(mrun[j], mx[j]);
      corr[j] = exp2f((mrun[j] - nm) * L2E);
      mrun[j] = nm;
    }
    #pragma unroll
    for (int cc = 0; cc < 4; ++cc)
      #pragma unroll
      for (int j = 0; j < 4; ++j)
        sc[cc][j] = exp2f((sc[cc][j] - mrun[j]) * L2E);
    float rs[4];
    #pragma unroll
    for (int j = 0; j < 4; ++j)
      rs[j] = sc[0][j] + sc[1][j] + sc[2][j] + sc[3][j];
    #pragma unroll
    for (int msk = 1; msk <= 8; msk <<= 1)
      #pragma unroll
      for (int j = 0; j < 4; ++j)
        rs[j] += __shfl_xor(rs[j], msk, 64);
    #pragma unroll
    for (int j = 0; j < 4; ++j)
      lrun[j] = lrun[j] * corr[j] + rs[j];
    #pragma unroll
    for (int dd = 0; dd < 4; ++dd)
      #pragma unroll
      for (int j = 0; j < 4; ++j)
        acc[dd][j] *= corr[j];

    #pragma unroll
    for (int cc = 0; cc < 4; ++cc)
      #pragma unroll
      for (int j = 0; j < 4; ++j)
        Ps[w][lg * 4 + j][cc * 16 + lr] = (__bf16)sc[cc][j];

    #pragma unroll
    for (int s = 0; s < 2; ++s) {
      bf16x8 pa = *(const bf16x8*)&Ps[w][lr][s * 32 + lg * 8];
      #pragma unroll
      for (int dd = 0; dd < 4; ++dd) {
        bf16x8 vf = *(const bf16x8*)&Vt[dd * 16 + lr][s * 32 + lg * 8];
        acc[dd] = __builtin_amdgcn_mfma_f32_16x16x32_bf16(pa, vf, acc[dd], 0, 0, 0);
      }
    }
    __syncthreads();
  }

  const int b = bh >> 4, h = bh & 15;
  #pragma unroll
  for (int dd = 0; dd < 4; ++dd)
    #pragma unroll
    for (int j = 0; j < 4; ++j) {
      int t = q0 + lg * 4 + j;
      int d = dd * 16 + lr;
      y[((size_t)(b * T_ + t)) * C_ + h * HD_ + d] = (__bf16)(acc[dd][j] / lrun[j]);
    }
}

// ---------------------------------------------------------------------------
extern "C" void kernel_launch(void* const* d_in, const int* in_sizes, int n_in,
                              void* d_out, int out_size, void* d_ws, size_t ws_size,
                              hipStream_t stream) {
  const float* x    = (const float*)d_in[0];
  const float* wqkv = (const float*)d_in[1];
  const float* bqkv = (const float*)d_in[2];
  const float* wo   = (const float*)d_in[3];
  const float* bo   = (const float*)d_in[4];
  float* out = (float*)d_out;

  char* ws = (char*)d_ws;
  const size_t MB = 1u << 20;
  __bf16* xb   = (__bf16*)(ws);              // 16 MB  x bf16 [8192][1024]
  __bf16* wqt  = (__bf16*)(ws + 16 * MB);    //  6 MB  w_qkv^T bf16 [3072][1024]
  __bf16* wot  = (__bf16*)(ws + 22 * MB);    //  2 MB  w_o^T bf16 [1024][1024]
  __bf16* qbuf = (__bf16*)(ws + 24 * MB);    // 16 MB  Q [B,H,T,HD]
  __bf16* kbuf = (__bf16*)(ws + 40 * MB);    // 16 MB  K
  __bf16* vbuf = (__bf16*)(ws + 56 * MB);    // 16 MB  V
  __bf16* ybuf = (__bf16*)(ws + 72 * MB);    // 16 MB  attn out [B,T,C]

  (void)hipFuncSetAttribute(reinterpret_cast<const void*>(&gemm8_kernel<0>),
                            hipFuncAttributeMaxDynamicSharedMemorySize, 98304);
  (void)hipFuncSetAttribute(reinterpret_cast<const void*>(&gemm8_kernel<1>),
                            hipFuncAttributeMaxDynamicSharedMemorySize, 98304);

  const int NX = B_ * T_ * C_;               // 8388608
  cvt_kernel<<<NX / (256 * 8), 256, 0, stream>>>(x, xb, NX);
  tconv_kernel<<<dim3(3 * C_ / 32, C_ / 32), dim3(32, 8), 0, stream>>>(wqkv, wqt, C_, 3 * C_);
  tconv_kernel<<<dim3(C_ / 32, C_ / 32), dim3(32, 8), 0, stream>>>(wo, wot, C_, C_);

  // QKV: M=8192, N=3072 -> 32 x 24 = 768 blocks (3.0 rounds of 256 CUs)
  gemm8_kernel<0><<<768, 512, 98304, stream>>>(
      xb, wqt, bqkv, B_ * T_, 3 * C_, C_, 24, qbuf, kbuf, vbuf, nullptr);

  attn_kernel<<<dim3(B_ * H_, T_ / 64), 256, 0, stream>>>(qbuf, kbuf, vbuf, ybuf);

  // out-proj: M=8192, N=1024 -> 32 x 8 = 256 blocks (1.0 round)
  gemm8_kernel<1><<<256, 512, 98304, stream>>>(
      ybuf, wot, bo, B_ * T_, C_, C_, 8, nullptr, nullptr, nullptr, out);
}